// Round 1
// baseline (2267.472 us; speedup 1.0000x reference)
//
#include <hip/hip_runtime.h>
#include <hip/hip_bf16.h>

// Problem constants
#define N_ROWS 8192
#define D1     1024
#define DF     256
#define KNB    32
#define LN_EPS 1e-5f

// ---------------------------------------------------------------------------
// LayerNorm: one block per row, 256 threads, 4 floats/thread (float4)
// ---------------------------------------------------------------------------
__global__ __launch_bounds__(256) void ln_kernel(const float* __restrict__ X,
                                                 const float* __restrict__ gamma,
                                                 const float* __restrict__ beta,
                                                 float* __restrict__ X1) {
    __shared__ float sa[4], sb[4];
    const int row = blockIdx.x;
    const int t = threadIdx.x;
    const float4 x = reinterpret_cast<const float4*>(X + (size_t)row * D1)[t];
    float s  = x.x + x.y + x.z + x.w;
    float ss = x.x * x.x + x.y * x.y + x.z * x.z + x.w * x.w;
#pragma unroll
    for (int o = 32; o > 0; o >>= 1) {
        s  += __shfl_down(s, o, 64);
        ss += __shfl_down(ss, o, 64);
    }
    const int w = t >> 6, l = t & 63;
    if (l == 0) { sa[w] = s; sb[w] = ss; }
    __syncthreads();
    s  = sa[0] + sa[1] + sa[2] + sa[3];
    ss = sb[0] + sb[1] + sb[2] + sb[3];
    const float mu  = s * (1.0f / D1);
    const float var = ss * (1.0f / D1) - mu * mu;
    const float rs  = rsqrtf(var + LN_EPS);
    const float4 g  = reinterpret_cast<const float4*>(gamma)[t];
    const float4 be = reinterpret_cast<const float4*>(beta)[t];
    float4 o;
    o.x = (x.x - mu) * rs * g.x + be.x;
    o.y = (x.y - mu) * rs * g.y + be.y;
    o.z = (x.z - mu) * rs * g.z + be.z;
    o.w = (x.w - mu) * rs * g.w + be.w;
    reinterpret_cast<float4*>(X1 + (size_t)row * D1)[t] = o;
}

// ---------------------------------------------------------------------------
// fp32 tiled GEMM: C[M,N] = A[M,K] * B(+bias). BM=BN=128, BK=16, 256 thr,
// 8x8 micro-tile per thread. TRANSB: B given as [N][K] row-major (fc_w).
// ---------------------------------------------------------------------------
template <bool TRANSB, bool BIAS>
__global__ __launch_bounds__(256) void gemm128(const float* __restrict__ A,
                                               const float* __restrict__ B,
                                               const float* __restrict__ bias,
                                               float* __restrict__ C,
                                               int M, int N, int K) {
    __shared__ float As[16][128];
    __shared__ float Bs[16][128];
    const int tid = threadIdx.x;
    const int bn = blockIdx.x * 128;
    const int bm = blockIdx.y * 128;
    const int tx = tid & 15, ty = tid >> 4;

    float acc[8][8];
#pragma unroll
    for (int i = 0; i < 8; ++i)
#pragma unroll
        for (int j = 0; j < 8; ++j) acc[i][j] = 0.0f;

    for (int k0 = 0; k0 < K; k0 += 16) {
        // A tile (transpose-on-write -> As[k][m])
#pragma unroll
        for (int c = 0; c < 2; ++c) {
            int idx = c * 256 + tid;          // 0..511
            int m = idx & 127, kg = idx >> 7; // kg 0..3
            float4 v = *reinterpret_cast<const float4*>(A + (size_t)(bm + m) * K + k0 + kg * 4);
            As[kg * 4 + 0][m] = v.x;
            As[kg * 4 + 1][m] = v.y;
            As[kg * 4 + 2][m] = v.z;
            As[kg * 4 + 3][m] = v.w;
        }
        if (TRANSB) {
#pragma unroll
            for (int c = 0; c < 2; ++c) {
                int idx = c * 256 + tid;
                int n = idx & 127, kg = idx >> 7;
                float4 v = *reinterpret_cast<const float4*>(B + (size_t)(bn + n) * K + k0 + kg * 4);
                Bs[kg * 4 + 0][n] = v.x;
                Bs[kg * 4 + 1][n] = v.y;
                Bs[kg * 4 + 2][n] = v.z;
                Bs[kg * 4 + 3][n] = v.w;
            }
        } else {
#pragma unroll
            for (int c = 0; c < 2; ++c) {
                int idx = c * 256 + tid;
                int n4 = idx & 31, kk = idx >> 5; // kk 0..15
                float4 v = *reinterpret_cast<const float4*>(B + (size_t)(k0 + kk) * N + bn + n4 * 4);
                *reinterpret_cast<float4*>(&Bs[kk][n4 * 4]) = v;
            }
        }
        __syncthreads();
#pragma unroll
        for (int kk = 0; kk < 16; ++kk) {
            float a[8], b[8];
            *reinterpret_cast<float4*>(&a[0]) = *reinterpret_cast<const float4*>(&As[kk][ty * 8]);
            *reinterpret_cast<float4*>(&a[4]) = *reinterpret_cast<const float4*>(&As[kk][ty * 8 + 4]);
            *reinterpret_cast<float4*>(&b[0]) = *reinterpret_cast<const float4*>(&Bs[kk][tx * 8]);
            *reinterpret_cast<float4*>(&b[4]) = *reinterpret_cast<const float4*>(&Bs[kk][tx * 8 + 4]);
#pragma unroll
            for (int i = 0; i < 8; ++i)
#pragma unroll
                for (int j = 0; j < 8; ++j) acc[i][j] += a[i] * b[j];
        }
        __syncthreads();
    }

#pragma unroll
    for (int i = 0; i < 8; ++i) {
        const int m = bm + ty * 8 + i;
        float* cp = C + (size_t)m * N + bn + tx * 8;
        float4 v0, v1;
        v0.x = acc[i][0]; v0.y = acc[i][1]; v0.z = acc[i][2]; v0.w = acc[i][3];
        v1.x = acc[i][4]; v1.y = acc[i][5]; v1.z = acc[i][6]; v1.w = acc[i][7];
        if (BIAS) {
            const float4 b0 = *reinterpret_cast<const float4*>(bias + bn + tx * 8);
            const float4 b1 = *reinterpret_cast<const float4*>(bias + bn + tx * 8 + 4);
            v0.x += b0.x; v0.y += b0.y; v0.z += b0.z; v0.w += b0.w;
            v1.x += b1.x; v1.y += b1.y; v1.z += b1.z; v1.w += b1.w;
        }
        *reinterpret_cast<float4*>(cp) = v0;
        *reinterpret_cast<float4*>(cp + 4) = v1;
    }
}

// ---------------------------------------------------------------------------
// Row L2-normalize: Xn = Xf / ||Xf||. One block per row, 256 threads = DF.
// ---------------------------------------------------------------------------
__global__ __launch_bounds__(256) void rownorm_kernel(const float* __restrict__ Xf,
                                                      float* __restrict__ Xn) {
    __shared__ float sa[4];
    const int row = blockIdx.x;
    const int t = threadIdx.x;
    const float v = Xf[(size_t)row * DF + t];
    float ss = v * v;
#pragma unroll
    for (int o = 32; o > 0; o >>= 1) ss += __shfl_down(ss, o, 64);
    const int w = t >> 6, l = t & 63;
    if (l == 0) sa[w] = ss;
    __syncthreads();
    ss = sa[0] + sa[1] + sa[2] + sa[3];
    const float inv = 1.0f / sqrtf(ss);
    Xn[(size_t)row * DF + t] = v * inv;
}

// ---------------------------------------------------------------------------
// Fused sim GEMM + top-32 + softmax.
// Block = 512 threads, owns 32 rows (A-tile in LDS). Streams j in chunks of
// 256 (one j per thread in each 256-thread half; 16 rows per thread in regs).
// Per-row top-32 maintained in LDS via filtered candidate queue + serial
// insertion (threads 0..31, one row each). Overflow-safe retry loop.
// Epilogue: softmax over the 32 kept values -> weights + indices.
// ---------------------------------------------------------------------------
#define QCAP 64

__global__ __launch_bounds__(512) void sim_topk_kernel(const float* __restrict__ Xn,
                                                       float* __restrict__ topw,
                                                       int* __restrict__ topig) {
    __shared__ float A[32][DF];        // 32 KB
    __shared__ float qv[32][QCAP];     // 8 KB
    __shared__ int   qj[32][QCAP];     // 8 KB
    __shared__ float topv[32][KNB];    // 4 KB
    __shared__ int   topi[32][KNB];    // 4 KB
    __shared__ float topmin[32];
    __shared__ int   qcnt[32];
    __shared__ int   ovf_flag;

    const int tid = threadIdx.x;
    const int i0 = blockIdx.x * 32;

    // Load A tile: 32 rows x 256 = 2048 float4, 512 threads -> 4 each
    for (int t = tid; t < 32 * (DF / 4); t += 512) {
        int r = t >> 6, k4 = t & 63;
        float4 v = reinterpret_cast<const float4*>(Xn + (size_t)(i0 + r) * DF)[k4];
        reinterpret_cast<float4*>(&A[r][0])[k4] = v;
    }
    if (tid < 32) {
        qcnt[tid] = 0;
        topmin[tid] = -__builtin_inff();
#pragma unroll
        for (int m = 0; m < KNB; ++m) { topv[tid][m] = -__builtin_inff(); topi[tid][m] = -1; }
    }
    if (tid == 0) ovf_flag = 0;
    __syncthreads();

    const int rg = tid >> 8;  // 0/1: which 16-row half this thread computes
    const int jl = tid & 255;
    const int r0 = rg * 16;

    for (int c = 0; c < N_ROWS / 256; ++c) {
        const int j = c * 256 + jl;
        const float4* bp = reinterpret_cast<const float4*>(Xn + (size_t)j * DF);
        float acc[16];
#pragma unroll
        for (int r = 0; r < 16; ++r) acc[r] = 0.0f;
#pragma unroll 4
        for (int k4 = 0; k4 < DF / 4; ++k4) {
            const float4 b = bp[k4];
#pragma unroll
            for (int r = 0; r < 16; ++r) {
                const float4 a = reinterpret_cast<const float4*>(&A[r0 + r][0])[k4];
                acc[r] += a.x * b.x + a.y * b.y + a.z * b.z + a.w * b.w;
            }
        }
        // ---- selection: filter -> queue -> serial insert (retry on overflow)
        unsigned pend = 0xFFFFu;
        for (;;) {
#pragma unroll
            for (int r = 0; r < 16; ++r) {
                if (pend & (1u << r)) {
                    const int row = r0 + r;
                    if (acc[r] > topmin[row]) {
                        int p = atomicAdd(&qcnt[row], 1);
                        if (p < QCAP) {
                            qv[row][p] = acc[r];
                            qj[row][p] = j;
                            pend &= ~(1u << r);
                        }
                    } else {
                        pend &= ~(1u << r);
                    }
                }
            }
            __syncthreads();  // queues ready
            if (tid < 32) {
                const int row = tid;
                int n = qcnt[row];
                if (n > QCAP) { ovf_flag = 1; n = QCAP; }
                for (int q = 0; q < n; ++q) {
                    const float v = qv[row][q];
                    if (v > topv[row][KNB - 1]) {
                        const int jj = qj[row][q];
                        int p = KNB - 1;
                        while (p > 0 && topv[row][p - 1] < v) {
                            topv[row][p] = topv[row][p - 1];
                            topi[row][p] = topi[row][p - 1];
                            --p;
                        }
                        topv[row][p] = v;
                        topi[row][p] = jj;
                    }
                }
                topmin[row] = topv[row][KNB - 1];
                qcnt[row] = 0;
            }
            __syncthreads();           // flag final
            const int f = ovf_flag;    // uniform read
            __syncthreads();           // everyone has read
            if (tid == 0) ovf_flag = 0;
            if (!f) break;
        }
    }

    // softmax over kept 32 values, write weights + indices
    if (tid < 32) {
        const int row = tid;
        const float m = topv[row][0];
        float w[KNB];
        float s = 0.0f;
#pragma unroll
        for (int q = 0; q < KNB; ++q) { w[q] = __expf(topv[row][q] - m); s += w[q]; }
        const float inv = 1.0f / s;
#pragma unroll
        for (int q = 0; q < KNB; ++q) {
            topw[(size_t)(i0 + row) * KNB + q] = w[q] * inv;
            topig[(size_t)(i0 + row) * KNB + q] = topi[row][q];
        }
    }
}

// ---------------------------------------------------------------------------
// out[i] = X[i] + gc_b + sum_m w[i][m] * H[idx[i][m]]   (G is row-stochastic,
// 32 nonzeros/row). One block per row, 256 threads, float4 per thread.
// ---------------------------------------------------------------------------
__global__ __launch_bounds__(256) void gather_kernel(const float* __restrict__ X,
                                                     const float* __restrict__ H,
                                                     const float* __restrict__ topw,
                                                     const int* __restrict__ topig,
                                                     const float* __restrict__ gc_b,
                                                     float* __restrict__ out) {
    __shared__ float w[KNB];
    __shared__ int   id[KNB];
    const int row = blockIdx.x;
    const int t = threadIdx.x;
    if (t < KNB) {
        w[t] = topw[(size_t)row * KNB + t];
        id[t] = topig[(size_t)row * KNB + t];
    }
    __syncthreads();
    const int col = t * 4;
    float4 acc = *reinterpret_cast<const float4*>(X + (size_t)row * D1 + col);
    const float4 b = *reinterpret_cast<const float4*>(gc_b + col);
    acc.x += b.x; acc.y += b.y; acc.z += b.z; acc.w += b.w;
#pragma unroll 8
    for (int m = 0; m < KNB; ++m) {
        const float wm = w[m];
        const float4 h = *reinterpret_cast<const float4*>(H + (size_t)id[m] * D1 + col);
        acc.x += wm * h.x; acc.y += wm * h.y; acc.z += wm * h.z; acc.w += wm * h.w;
    }
    *reinterpret_cast<float4*>(out + (size_t)row * D1 + col) = acc;
}

// ---------------------------------------------------------------------------
extern "C" void kernel_launch(void* const* d_in, const int* in_sizes, int n_in,
                              void* d_out, int out_size, void* d_ws, size_t ws_size,
                              hipStream_t stream) {
    const float* X  = (const float*)d_in[0];
    const float* lg = (const float*)d_in[1];
    const float* lb = (const float*)d_in[2];
    const float* fw = (const float*)d_in[3];
    const float* fb = (const float*)d_in[4];
    const float* gw = (const float*)d_in[5];
    const float* gb = (const float*)d_in[6];
    float* out = (float*)d_out;

    // workspace layout (floats)
    const size_t szX1 = (size_t)N_ROWS * D1;
    const size_t szXf = (size_t)N_ROWS * DF;
    const size_t need = (szX1 + szXf * 2 + szX1 + (size_t)N_ROWS * KNB * 2) * sizeof(float);
    if (ws_size < need) return;  // workspace too small -> fail loudly (no corruption)

    float* ws = (float*)d_ws;
    float* X1 = ws;
    float* Xf = X1 + szX1;
    float* Xn = Xf + szXf;
    float* H  = Xn + szXf;
    float* tw = H + szX1;
    int*   ti = (int*)(tw + (size_t)N_ROWS * KNB);

    ln_kernel<<<N_ROWS, 256, 0, stream>>>(X, lg, lb, X1);
    gemm128<true, true><<<dim3(DF / 128, N_ROWS / 128), 256, 0, stream>>>(X1, fw, fb, Xf, N_ROWS, DF, D1);
    rownorm_kernel<<<N_ROWS, 256, 0, stream>>>(Xf, Xn);
    sim_topk_kernel<<<N_ROWS / 32, 512, 0, stream>>>(Xn, tw, ti);
    gemm128<false, false><<<dim3(D1 / 128, N_ROWS / 128), 256, 0, stream>>>(X1, gw, nullptr, H, N_ROWS, D1, D1);
    gather_kernel<<<N_ROWS, 256, 0, stream>>>(X, H, tw, ti, gb, out);
}

// Round 5
// 1738.784 us; speedup vs baseline: 1.3041x; 1.3041x over previous
//
#include <hip/hip_runtime.h>
#include <hip/hip_bf16.h>

// Problem constants
#define N_ROWS 8192
#define D1     1024
#define DF     256
#define KNB    32
#define LN_EPS 1e-5f

// ---------------------------------------------------------------------------
// LayerNorm: one block per row, 256 threads, 4 floats/thread (float4)
// ---------------------------------------------------------------------------
__global__ __launch_bounds__(256) void ln_kernel(const float* __restrict__ X,
                                                 const float* __restrict__ gamma,
                                                 const float* __restrict__ beta,
                                                 float* __restrict__ X1) {
    __shared__ float sa[4], sb[4];
    const int row = blockIdx.x;
    const int t = threadIdx.x;
    const float4 x = reinterpret_cast<const float4*>(X + (size_t)row * D1)[t];
    float s  = x.x + x.y + x.z + x.w;
    float ss = x.x * x.x + x.y * x.y + x.z * x.z + x.w * x.w;
#pragma unroll
    for (int o = 32; o > 0; o >>= 1) {
        s  += __shfl_down(s, o, 64);
        ss += __shfl_down(ss, o, 64);
    }
    const int w = t >> 6, l = t & 63;
    if (l == 0) { sa[w] = s; sb[w] = ss; }
    __syncthreads();
    s  = sa[0] + sa[1] + sa[2] + sa[3];
    ss = sb[0] + sb[1] + sb[2] + sb[3];
    const float mu  = s * (1.0f / D1);
    const float var = ss * (1.0f / D1) - mu * mu;
    const float rs  = rsqrtf(var + LN_EPS);
    const float4 g  = reinterpret_cast<const float4*>(gamma)[t];
    const float4 be = reinterpret_cast<const float4*>(beta)[t];
    float4 o;
    o.x = (x.x - mu) * rs * g.x + be.x;
    o.y = (x.y - mu) * rs * g.y + be.y;
    o.z = (x.z - mu) * rs * g.z + be.z;
    o.w = (x.w - mu) * rs * g.w + be.w;
    reinterpret_cast<float4*>(X1 + (size_t)row * D1)[t] = o;
}

// ---------------------------------------------------------------------------
// fp32 tiled GEMM: C[M,N] = A[M,K] * B(+bias). BM=BN=128, BK=16, 256 thr,
// 8x8 micro-tile per thread. TRANSB: B given as [N][K] row-major (fc_w).
// ---------------------------------------------------------------------------
template <bool TRANSB, bool BIAS>
__global__ __launch_bounds__(256) void gemm128(const float* __restrict__ A,
                                               const float* __restrict__ B,
                                               const float* __restrict__ bias,
                                               float* __restrict__ C,
                                               int M, int N, int K) {
    __shared__ float As[16][128];
    __shared__ float Bs[16][128];
    const int tid = threadIdx.x;
    const int bn = blockIdx.x * 128;
    const int bm = blockIdx.y * 128;
    const int tx = tid & 15, ty = tid >> 4;

    float acc[8][8];
#pragma unroll
    for (int i = 0; i < 8; ++i)
#pragma unroll
        for (int j = 0; j < 8; ++j) acc[i][j] = 0.0f;

    for (int k0 = 0; k0 < K; k0 += 16) {
        // A tile (transpose-on-write -> As[k][m])
#pragma unroll
        for (int c = 0; c < 2; ++c) {
            int idx = c * 256 + tid;          // 0..511
            int m = idx & 127, kg = idx >> 7; // kg 0..3
            float4 v = *reinterpret_cast<const float4*>(A + (size_t)(bm + m) * K + k0 + kg * 4);
            As[kg * 4 + 0][m] = v.x;
            As[kg * 4 + 1][m] = v.y;
            As[kg * 4 + 2][m] = v.z;
            As[kg * 4 + 3][m] = v.w;
        }
        if (TRANSB) {
#pragma unroll
            for (int c = 0; c < 2; ++c) {
                int idx = c * 256 + tid;
                int n = idx & 127, kg = idx >> 7;
                float4 v = *reinterpret_cast<const float4*>(B + (size_t)(bn + n) * K + k0 + kg * 4);
                Bs[kg * 4 + 0][n] = v.x;
                Bs[kg * 4 + 1][n] = v.y;
                Bs[kg * 4 + 2][n] = v.z;
                Bs[kg * 4 + 3][n] = v.w;
            }
        } else {
#pragma unroll
            for (int c = 0; c < 2; ++c) {
                int idx = c * 256 + tid;
                int n4 = idx & 31, kk = idx >> 5; // kk 0..15
                float4 v = *reinterpret_cast<const float4*>(B + (size_t)(k0 + kk) * N + bn + n4 * 4);
                *reinterpret_cast<float4*>(&Bs[kk][n4 * 4]) = v;
            }
        }
        __syncthreads();
#pragma unroll
        for (int kk = 0; kk < 16; ++kk) {
            float a[8], b[8];
            *reinterpret_cast<float4*>(&a[0]) = *reinterpret_cast<const float4*>(&As[kk][ty * 8]);
            *reinterpret_cast<float4*>(&a[4]) = *reinterpret_cast<const float4*>(&As[kk][ty * 8 + 4]);
            *reinterpret_cast<float4*>(&b[0]) = *reinterpret_cast<const float4*>(&Bs[kk][tx * 8]);
            *reinterpret_cast<float4*>(&b[4]) = *reinterpret_cast<const float4*>(&Bs[kk][tx * 8 + 4]);
#pragma unroll
            for (int i = 0; i < 8; ++i)
#pragma unroll
                for (int j = 0; j < 8; ++j) acc[i][j] += a[i] * b[j];
        }
        __syncthreads();
    }

#pragma unroll
    for (int i = 0; i < 8; ++i) {
        const int m = bm + ty * 8 + i;
        float* cp = C + (size_t)m * N + bn + tx * 8;
        float4 v0, v1;
        v0.x = acc[i][0]; v0.y = acc[i][1]; v0.z = acc[i][2]; v0.w = acc[i][3];
        v1.x = acc[i][4]; v1.y = acc[i][5]; v1.z = acc[i][6]; v1.w = acc[i][7];
        if (BIAS) {
            const float4 b0 = *reinterpret_cast<const float4*>(bias + bn + tx * 8);
            const float4 b1 = *reinterpret_cast<const float4*>(bias + bn + tx * 8 + 4);
            v0.x += b0.x; v0.y += b0.y; v0.z += b0.z; v0.w += b0.w;
            v1.x += b1.x; v1.y += b1.y; v1.z += b1.z; v1.w += b1.w;
        }
        *reinterpret_cast<float4*>(cp) = v0;
        *reinterpret_cast<float4*>(cp + 4) = v1;
    }
}

// ---------------------------------------------------------------------------
// Row L2-normalize: Xn = Xf / ||Xf||. One block per row, 256 threads = DF.
// ---------------------------------------------------------------------------
__global__ __launch_bounds__(256) void rownorm_kernel(const float* __restrict__ Xf,
                                                      float* __restrict__ Xn) {
    __shared__ float sa[4];
    const int row = blockIdx.x;
    const int t = threadIdx.x;
    const float v = Xf[(size_t)row * DF + t];
    float ss = v * v;
#pragma unroll
    for (int o = 32; o > 0; o >>= 1) ss += __shfl_down(ss, o, 64);
    const int w = t >> 6, l = t & 63;
    if (l == 0) sa[w] = ss;
    __syncthreads();
    ss = sa[0] + sa[1] + sa[2] + sa[3];
    const float inv = 1.0f / sqrtf(ss);
    Xn[(size_t)row * DF + t] = v * inv;
}

// ---------------------------------------------------------------------------
// Fused sim GEMM + top-32 + softmax, v2.
// 512 threads/block, block owns BM=32 rows. A-tile transposed in LDS
// ([k][r], broadcast reads). j streamed in BN=256 chunks; B-tile [BK][BN+4]
// staged via register prefetch (issue loads during previous compute phase).
// Micro-tile 4 rows x 4 j per thread: per kk = 1 broadcast A read + 1
// conflict-free B read per 16 FMA -> VALU-bound.
// Selection: filtered candidate queue + serial insert (threads 0..31), all
// selection LDS rows padded to kill same-bank strides. Overflow-safe retry.
// ---------------------------------------------------------------------------
#define BM 32
#define BN 256
#define BK 32
#define QCAP 64
#define NSTAGE (DF / BK)                 // 8 stages per chunk
#define NCHUNK (N_ROWS / BN)             // 32 chunks
#define TOTSTAGE (NSTAGE * NCHUNK)       // 256

__global__ __launch_bounds__(512) void sim_topk_kernel(const float* __restrict__ Xn,
                                                       float* __restrict__ topw,
                                                       int* __restrict__ topig) {
    __shared__ float As[DF][BM];          // 32 KB, [k][r] transposed
    __shared__ float Bs[BK][BN + 4];      // 33.3 KB, [k][j] padded (16B-aligned rows)
    __shared__ float topv[BM][KNB + 1];   // padded: bank = (row*33+q)%32 varies
    __shared__ int   topi[BM][KNB + 1];
    __shared__ float qv[BM][QCAP + 1];
    __shared__ int   qj[BM][QCAP + 1];
    __shared__ float topmin[BM];
    __shared__ int   qcnt[BM];
    __shared__ int   ovf_flag;

    const int tid = threadIdx.x;
    const int i0 = blockIdx.x * BM;
    const int tx = tid & 63;              // j-group: columns tx*4..tx*4+3
    const int ty = tid >> 6;              // row-group 0..7
    const int r0 = ty * 4;

    // ---- A tile stage (once): coalesced-ish read, conflict-free transposed write
    // idx = c*512+tid -> r = tid&31, k4 = c*16 + (tid>>5)
    {
        const int r = tid & 31;
        const int k4b = tid >> 5;         // 0..15
#pragma unroll
        for (int c = 0; c < 4; ++c) {
            const int k4 = c * 16 + k4b;
            const float4 v = *reinterpret_cast<const float4*>(Xn + (size_t)(i0 + r) * DF + k4 * 4);
            As[k4 * 4 + 0][r] = v.x;      // bank = r%32, distinct per lane
            As[k4 * 4 + 1][r] = v.y;
            As[k4 * 4 + 2][r] = v.z;
            As[k4 * 4 + 3][r] = v.w;
        }
    }
    if (tid < BM) {
        qcnt[tid] = 0;
        topmin[tid] = -__builtin_inff();
#pragma unroll
        for (int m = 0; m < KNB; ++m) { topv[tid][m] = -__builtin_inff(); topi[tid][m] = -1; }
    }
    if (tid == 0) ovf_flag = 0;

    // ---- B staging thread mapping: kg = tid&7 (k-float4), jjb = tid>>3 (j)
    const int kg = tid & 7;               // covers BK=32 as kg*4 + c-offset below
    const int jjb = tid >> 3;             // 0..63
    // per c: jj = c*64 + jjb, k-offset = kg*4 (+ constant per stage)

    // prefetch stage 0 (chunk 0, k0 = 0) into registers
    float4 pv[4];
#pragma unroll
    for (int c = 0; c < 4; ++c) {
        const int jj = c * 64 + jjb;
        pv[c] = *reinterpret_cast<const float4*>(Xn + (size_t)jj * DF + kg * 4);
    }

    float acc[4][4];

    for (int s = 0; s < TOTSTAGE; ++s) {
        const int k0 = (s & (NSTAGE - 1)) * BK;
        __syncthreads();                  // Bs free (prev compute done) / init+A done
        // write prefetched regs -> Bs
#pragma unroll
        for (int c = 0; c < 4; ++c) {
            const int jj = c * 64 + jjb;
            Bs[kg * 4 + 0][jj] = pv[c].x;
            Bs[kg * 4 + 1][jj] = pv[c].y;
            Bs[kg * 4 + 2][jj] = pv[c].z;
            Bs[kg * 4 + 3][jj] = pv[c].w;
        }
        // issue next stage's loads (latency hides under compute below)
        if (s + 1 < TOTSTAGE) {
            const int k0n = ((s + 1) & (NSTAGE - 1)) * BK;
            const size_t jbn = (size_t)((s + 1) >> 3) * BN;  // (s+1)/NSTAGE * BN
#pragma unroll
            for (int c = 0; c < 4; ++c) {
                const int jj = c * 64 + jjb;
                pv[c] = *reinterpret_cast<const float4*>(Xn + (jbn + jj) * DF + k0n + kg * 4);
            }
        }
        __syncthreads();                  // Bs ready

        if (k0 == 0) {
#pragma unroll
            for (int r = 0; r < 4; ++r)
#pragma unroll
                for (int j = 0; j < 4; ++j) acc[r][j] = 0.0f;
        }
#pragma unroll
        for (int kk = 0; kk < BK; ++kk) {
            const float4 a = *reinterpret_cast<const float4*>(&As[k0 + kk][r0]);   // wave-uniform broadcast
            const float4 b = *reinterpret_cast<const float4*>(&Bs[kk][tx * 4]);    // contiguous, conflict-free
            acc[0][0] = fmaf(a.x, b.x, acc[0][0]); acc[0][1] = fmaf(a.x, b.y, acc[0][1]);
            acc[0][2] = fmaf(a.x, b.z, acc[0][2]); acc[0][3] = fmaf(a.x, b.w, acc[0][3]);
            acc[1][0] = fmaf(a.y, b.x, acc[1][0]); acc[1][1] = fmaf(a.y, b.y, acc[1][1]);
            acc[1][2] = fmaf(a.y, b.z, acc[1][2]); acc[1][3] = fmaf(a.y, b.w, acc[1][3]);
            acc[2][0] = fmaf(a.z, b.x, acc[2][0]); acc[2][1] = fmaf(a.z, b.y, acc[2][1]);
            acc[2][2] = fmaf(a.z, b.z, acc[2][2]); acc[2][3] = fmaf(a.z, b.w, acc[2][3]);
            acc[3][0] = fmaf(a.w, b.x, acc[3][0]); acc[3][1] = fmaf(a.w, b.y, acc[3][1]);
            acc[3][2] = fmaf(a.w, b.z, acc[3][2]); acc[3][3] = fmaf(a.w, b.w, acc[3][3]);
        }

        if ((s & (NSTAGE - 1)) == NSTAGE - 1) {
            // ---- selection for completed chunk
            const int jb = (s >> 3) * BN;     // s/NSTAGE * BN
            unsigned pend = 0xFFFFu;          // bit = r*4+j
            for (;;) {
#pragma unroll
                for (int r = 0; r < 4; ++r) {
#pragma unroll
                    for (int j = 0; j < 4; ++j) {
                        const int bit = r * 4 + j;
                        if (pend & (1u << bit)) {
                            const int row = r0 + r;
                            if (acc[r][j] > topmin[row]) {
                                const int p = atomicAdd(&qcnt[row], 1);
                                if (p < QCAP) {
                                    qv[row][p] = acc[r][j];
                                    qj[row][p] = jb + tx * 4 + j;
                                    pend &= ~(1u << bit);
                                }
                            } else {
                                pend &= ~(1u << bit);
                            }
                        }
                    }
                }
                __syncthreads();              // queues ready
                if (tid < BM) {
                    const int row = tid;
                    int n = qcnt[row];
                    if (n > QCAP) { ovf_flag = 1; n = QCAP; }
                    for (int q = 0; q < n; ++q) {
                        const float v = qv[row][q];
                        if (v > topv[row][KNB - 1]) {
                            const int jjx = qj[row][q];
                            int p = KNB - 1;
                            while (p > 0 && topv[row][p - 1] < v) {
                                topv[row][p] = topv[row][p - 1];
                                topi[row][p] = topi[row][p - 1];
                                --p;
                            }
                            topv[row][p] = v;
                            topi[row][p] = jjx;
                        }
                    }
                    topmin[row] = topv[row][KNB - 1];
                    qcnt[row] = 0;
                }
                __syncthreads();              // flag final
                const int f = ovf_flag;       // uniform read
                __syncthreads();              // everyone has read
                if (tid == 0) ovf_flag = 0;
                if (!f) break;
            }
        }
    }

    // softmax over kept 32 values, write weights + indices
    if (tid < BM) {
        const int row = tid;
        const float m = topv[row][0];
        float w[KNB];
        float s = 0.0f;
#pragma unroll
        for (int q = 0; q < KNB; ++q) { w[q] = __expf(topv[row][q] - m); s += w[q]; }
        const float inv = 1.0f / s;
#pragma unroll
        for (int q = 0; q < KNB; ++q) {
            topw[(size_t)(i0 + row) * KNB + q] = w[q] * inv;
            topig[(size_t)(i0 + row) * KNB + q] = topi[row][q];
        }
    }
}

// ---------------------------------------------------------------------------
// out[i] = X[i] + gc_b + sum_m w[i][m] * H[idx[i][m]]   (G is row-stochastic,
// 32 nonzeros/row). One block per row, 256 threads, float4 per thread.
// ---------------------------------------------------------------------------
__global__ __launch_bounds__(256) void gather_kernel(const float* __restrict__ X,
                                                     const float* __restrict__ H,
                                                     const float* __restrict__ topw,
                                                     const int* __restrict__ topig,
                                                     const float* __restrict__ gc_b,
                                                     float* __restrict__ out) {
    __shared__ float w[KNB];
    __shared__ int   id[KNB];
    const int row = blockIdx.x;
    const int t = threadIdx.x;
    if (t < KNB) {
        w[t] = topw[(size_t)row * KNB + t];
        id[t] = topig[(size_t)row * KNB + t];
    }
    __syncthreads();
    const int col = t * 4;
    float4 acc = *reinterpret_cast<const float4*>(X + (size_t)row * D1 + col);
    const float4 b = *reinterpret_cast<const float4*>(gc_b + col);
    acc.x += b.x; acc.y += b.y; acc.z += b.z; acc.w += b.w;
#pragma unroll 8
    for (int m = 0; m < KNB; ++m) {
        const float wm = w[m];
        const float4 h = *reinterpret_cast<const float4*>(H + (size_t)id[m] * D1 + col);
        acc.x += wm * h.x; acc.y += wm * h.y; acc.z += wm * h.z; acc.w += wm * h.w;
    }
    *reinterpret_cast<float4*>(out + (size_t)row * D1 + col) = acc;
}

// ---------------------------------------------------------------------------
extern "C" void kernel_launch(void* const* d_in, const int* in_sizes, int n_in,
                              void* d_out, int out_size, void* d_ws, size_t ws_size,
                              hipStream_t stream) {
    const float* X  = (const float*)d_in[0];
    const float* lg = (const float*)d_in[1];
    const float* lb = (const float*)d_in[2];
    const float* fw = (const float*)d_in[3];
    const float* fb = (const float*)d_in[4];
    const float* gw = (const float*)d_in[5];
    const float* gb = (const float*)d_in[6];
    float* out = (float*)d_out;

    // workspace layout (floats)
    const size_t szX1 = (size_t)N_ROWS * D1;
    const size_t szXf = (size_t)N_ROWS * DF;
    const size_t need = (szX1 + szXf * 2 + szX1 + (size_t)N_ROWS * KNB * 2) * sizeof(float);
    if (ws_size < need) return;  // workspace too small -> fail loudly (no corruption)

    float* ws = (float*)d_ws;
    float* X1 = ws;
    float* Xf = X1 + szX1;
    float* Xn = Xf + szXf;
    float* H  = Xn + szXf;
    float* tw = H + szX1;
    int*   ti = (int*)(tw + (size_t)N_ROWS * KNB);

    ln_kernel<<<N_ROWS, 256, 0, stream>>>(X, lg, lb, X1);
    gemm128<true, true><<<dim3(DF / 128, N_ROWS / 128), 256, 0, stream>>>(X1, fw, fb, Xf, N_ROWS, DF, D1);
    rownorm_kernel<<<N_ROWS, 256, 0, stream>>>(Xf, Xn);
    sim_topk_kernel<<<N_ROWS / BM, 512, 0, stream>>>(Xn, tw, ti);
    gemm128<false, false><<<dim3(D1 / 128, N_ROWS / 128), 256, 0, stream>>>(X1, gw, nullptr, H, N_ROWS, D1, D1);
    gather_kernel<<<N_ROWS, 256, 0, stream>>>(X, H, tw, ti, gb, out);
}

// Round 6
// 1498.289 us; speedup vs baseline: 1.5134x; 1.1605x over previous
//
#include <hip/hip_runtime.h>
#include <hip/hip_bf16.h>

// Problem constants
#define N_ROWS 8192
#define D1     1024
#define DF     256
#define KNB    32
#define LN_EPS 1e-5f

typedef __attribute__((ext_vector_type(8)))  short short8v;   // 8 bf16 (4 VGPRs)
typedef __attribute__((ext_vector_type(16))) float f32x16;    // MFMA 32x32 accumulator

// ---------------------------------------------------------------------------
// LayerNorm: one block per row, 256 threads, 4 floats/thread (float4)
// ---------------------------------------------------------------------------
__global__ __launch_bounds__(256) void ln_kernel(const float* __restrict__ X,
                                                 const float* __restrict__ gamma,
                                                 const float* __restrict__ beta,
                                                 float* __restrict__ X1) {
    __shared__ float sa[4], sb[4];
    const int row = blockIdx.x;
    const int t = threadIdx.x;
    const float4 x = reinterpret_cast<const float4*>(X + (size_t)row * D1)[t];
    float s  = x.x + x.y + x.z + x.w;
    float ss = x.x * x.x + x.y * x.y + x.z * x.z + x.w * x.w;
#pragma unroll
    for (int o = 32; o > 0; o >>= 1) {
        s  += __shfl_down(s, o, 64);
        ss += __shfl_down(ss, o, 64);
    }
    const int w = t >> 6, l = t & 63;
    if (l == 0) { sa[w] = s; sb[w] = ss; }
    __syncthreads();
    s  = sa[0] + sa[1] + sa[2] + sa[3];
    ss = sb[0] + sb[1] + sb[2] + sb[3];
    const float mu  = s * (1.0f / D1);
    const float var = ss * (1.0f / D1) - mu * mu;
    const float rs  = rsqrtf(var + LN_EPS);
    const float4 g  = reinterpret_cast<const float4*>(gamma)[t];
    const float4 be = reinterpret_cast<const float4*>(beta)[t];
    float4 o;
    o.x = (x.x - mu) * rs * g.x + be.x;
    o.y = (x.y - mu) * rs * g.y + be.y;
    o.z = (x.z - mu) * rs * g.z + be.z;
    o.w = (x.w - mu) * rs * g.w + be.w;
    reinterpret_cast<float4*>(X1 + (size_t)row * D1)[t] = o;
}

// ---------------------------------------------------------------------------
// fp32 tiled GEMM (unchanged from v2 — handles fc and gc matmuls)
// ---------------------------------------------------------------------------
template <bool TRANSB, bool BIAS>
__global__ __launch_bounds__(256) void gemm128(const float* __restrict__ A,
                                               const float* __restrict__ B,
                                               const float* __restrict__ bias,
                                               float* __restrict__ C,
                                               int M, int N, int K) {
    __shared__ float As[16][128];
    __shared__ float Bs[16][128];
    const int tid = threadIdx.x;
    const int bn = blockIdx.x * 128;
    const int bm = blockIdx.y * 128;
    const int tx = tid & 15, ty = tid >> 4;

    float acc[8][8];
#pragma unroll
    for (int i = 0; i < 8; ++i)
#pragma unroll
        for (int j = 0; j < 8; ++j) acc[i][j] = 0.0f;

    for (int k0 = 0; k0 < K; k0 += 16) {
#pragma unroll
        for (int c = 0; c < 2; ++c) {
            int idx = c * 256 + tid;
            int m = idx & 127, kg = idx >> 7;
            float4 v = *reinterpret_cast<const float4*>(A + (size_t)(bm + m) * K + k0 + kg * 4);
            As[kg * 4 + 0][m] = v.x;
            As[kg * 4 + 1][m] = v.y;
            As[kg * 4 + 2][m] = v.z;
            As[kg * 4 + 3][m] = v.w;
        }
        if (TRANSB) {
#pragma unroll
            for (int c = 0; c < 2; ++c) {
                int idx = c * 256 + tid;
                int n = idx & 127, kg = idx >> 7;
                float4 v = *reinterpret_cast<const float4*>(B + (size_t)(bn + n) * K + k0 + kg * 4);
                Bs[kg * 4 + 0][n] = v.x;
                Bs[kg * 4 + 1][n] = v.y;
                Bs[kg * 4 + 2][n] = v.z;
                Bs[kg * 4 + 3][n] = v.w;
            }
        } else {
#pragma unroll
            for (int c = 0; c < 2; ++c) {
                int idx = c * 256 + tid;
                int n4 = idx & 31, kk = idx >> 5;
                float4 v = *reinterpret_cast<const float4*>(B + (size_t)(k0 + kk) * N + bn + n4 * 4);
                *reinterpret_cast<float4*>(&Bs[kk][n4 * 4]) = v;
            }
        }
        __syncthreads();
#pragma unroll
        for (int kk = 0; kk < 16; ++kk) {
            float a[8], b[8];
            *reinterpret_cast<float4*>(&a[0]) = *reinterpret_cast<const float4*>(&As[kk][ty * 8]);
            *reinterpret_cast<float4*>(&a[4]) = *reinterpret_cast<const float4*>(&As[kk][ty * 8 + 4]);
            *reinterpret_cast<float4*>(&b[0]) = *reinterpret_cast<const float4*>(&Bs[kk][tx * 8]);
            *reinterpret_cast<float4*>(&b[4]) = *reinterpret_cast<const float4*>(&Bs[kk][tx * 8 + 4]);
#pragma unroll
            for (int i = 0; i < 8; ++i)
#pragma unroll
                for (int j = 0; j < 8; ++j) acc[i][j] += a[i] * b[j];
        }
        __syncthreads();
    }

#pragma unroll
    for (int i = 0; i < 8; ++i) {
        const int m = bm + ty * 8 + i;
        float* cp = C + (size_t)m * N + bn + tx * 8;
        float4 v0, v1;
        v0.x = acc[i][0]; v0.y = acc[i][1]; v0.z = acc[i][2]; v0.w = acc[i][3];
        v1.x = acc[i][4]; v1.y = acc[i][5]; v1.z = acc[i][6]; v1.w = acc[i][7];
        if (BIAS) {
            const float4 b0 = *reinterpret_cast<const float4*>(bias + bn + tx * 8);
            const float4 b1 = *reinterpret_cast<const float4*>(bias + bn + tx * 8 + 4);
            v0.x += b0.x; v0.y += b0.y; v0.z += b0.z; v0.w += b0.w;
            v1.x += b1.x; v1.y += b1.y; v1.z += b1.z; v1.w += b1.w;
        }
        *reinterpret_cast<float4*>(cp) = v0;
        *reinterpret_cast<float4*>(cp + 4) = v1;
    }
}

// ---------------------------------------------------------------------------
// Row L2-normalize + split-bf16 emit: xhi = bf16(xn), xlo = bf16(xn - xhi).
// One block per row, 256 threads = DF.
// ---------------------------------------------------------------------------
__global__ __launch_bounds__(256) void rownorm_kernel(const float* __restrict__ Xf,
                                                      __hip_bfloat16* __restrict__ xhi,
                                                      __hip_bfloat16* __restrict__ xlo) {
    __shared__ float sa[4];
    const int row = blockIdx.x;
    const int t = threadIdx.x;
    const float v = Xf[(size_t)row * DF + t];
    float ss = v * v;
#pragma unroll
    for (int o = 32; o > 0; o >>= 1) ss += __shfl_down(ss, o, 64);
    const int w = t >> 6, l = t & 63;
    if (l == 0) sa[w] = ss;
    __syncthreads();
    ss = sa[0] + sa[1] + sa[2] + sa[3];
    const float inv = 1.0f / sqrtf(ss);
    const float xn = v * inv;
    const __hip_bfloat16 h = __float2bfloat16(xn);
    const float hf = __bfloat162float(h);
    const __hip_bfloat16 lo = __float2bfloat16(xn - hf);
    xhi[(size_t)row * DF + t] = h;
    xlo[(size_t)row * DF + t] = lo;
}

// ---------------------------------------------------------------------------
// Fused sim GEMM + top-32 + softmax, v3: split-bf16 MFMA.
// S = Xn·Xn^T computed as hi·hi + hi·lo + lo·hi (3 MFMA passes, err ~2^-16).
// Block = 32 rows (i0..i0+31), 512 threads = 8 waves. A hi/lo fragments for
// the full K=256 live in registers (32 frags x 4 VGPR). B streamed in chunks
// of 256 j-cols x 64 k via global_load_lds (16B, per-lane swizzled source ->
// linear LDS dest, frag-native [slot][j] layout -> conflict-free ds_read_b128).
// Double-buffered, counted vmcnt(8), raw s_barrier + sched_barrier fences.
// Selection: v2's proven queue + serial-insert + retry, verbatim.
//
// MFMA layouts (m74/m101 verified, 32x32x16_bf16):
//   A: row = lane&31, k = (lane>>5)*8 + i
//   B: col = lane&31, k = (lane>>5)*8 + i
//   C: col = lane&31, row = (reg&3) + 8*(reg>>2) + 4*(lane>>5)
// ---------------------------------------------------------------------------
#define QCAP   64
#define NCHUNK 32     // 8192 / 256 cols
#define NSTG   128    // NCHUNK * 4 k-stages (64 k each)

__global__ __launch_bounds__(512, 2) void sim_topk_kernel(
        const __hip_bfloat16* __restrict__ xhi_p,
        const __hip_bfloat16* __restrict__ xlo_p,
        float* __restrict__ topw,
        int* __restrict__ topig) {
    // B buffers: [buf 2][hl 2][slot 8][j 256][16B] = 128 KB
    __shared__ char  bbuf[131072];
    __shared__ float topv[32][KNB + 1];
    __shared__ int   topi[32][KNB + 1];
    __shared__ float qv[32][QCAP + 1];
    __shared__ int   qj[32][QCAP + 1];
    __shared__ float topmin[32];
    __shared__ int   qcnt[32];
    __shared__ int   ovf_flag;

    const int tid  = threadIdx.x;
    const int lane = tid & 63;
    const int wid  = tid >> 6;       // wave 0..7 -> owns cols wid*32..wid*32+31 of chunk
    const int lh   = lane >> 5;      // k-half selector / C-row offset
    const int lm   = lane & 31;
    const int i0   = blockIdx.x * 32;

    const char* xhb = (const char*)xhi_p;
    const char* xlb = (const char*)xlo_p;

    // ---- A fragments in registers: 16 k-tiles x {hi,lo}
    short8v ahi[16], alo[16];
    {
        const size_t ab = (size_t)(i0 + lm) * 512 + (size_t)(lh * 16);
#pragma unroll
        for (int kt = 0; kt < 16; ++kt) {
            ahi[kt] = *(const short8v*)(xhb + ab + kt * 32);
            alo[kt] = *(const short8v*)(xlb + ab + kt * 32);
        }
    }

    // ---- selection init
    if (tid < 32) {
        qcnt[tid] = 0;
        topmin[tid] = -__builtin_inff();
#pragma unroll
        for (int m = 0; m < KNB; ++m) { topv[tid][m] = -__builtin_inff(); topi[tid][m] = -1; }
    }
    if (tid == 0) ovf_flag = 0;
    __syncthreads();   // full fence: init + nothing stale

    // stage S covers chunk S>>2, k-range ((S&3)*64 .. +64). Each wave issues 8
    // global_load_lds(16B): gi = wid*8+q -> sc = gi>>2 (0..15: hl*8+slot),
    // g = gi&3 (j-group of 64). LDS dest linear (lane*16); global src per-lane.
#define ISSUE_STAGE(S) do {                                                          \
        const int cn_ = (S) >> 2;                                                    \
        const int kb_ = ((S) & 3) * 128; /* k0 bytes */                              \
        const int b_  = (S) & 1;                                                     \
        _Pragma("unroll")                                                            \
        for (int q = 0; q < 8; ++q) {                                                \
            const int gi   = (wid << 3) + q;                                         \
            const int sc   = gi >> 2;                                                \
            const int g    = gi & 3;                                                 \
            const int hl   = sc >> 3;                                                \
            const int slot = sc & 7;                                                 \
            const char* src = (hl ? xlb : xhb)                                       \
                + (size_t)(cn_ * 256 + g * 64 + lane) * 512                          \
                + (size_t)(kb_ + (slot >> 1) * 32 + (slot & 1) * 16);                \
            char* dst = bbuf + (((b_ << 4) + (hl << 3) + slot) << 12) + (g << 10);   \
            __builtin_amdgcn_global_load_lds(                                        \
                (const __attribute__((address_space(1))) unsigned int*)src,          \
                (__attribute__((address_space(3))) unsigned int*)dst, 16, 0, 0);     \
        }                                                                            \
    } while (0)

    ISSUE_STAGE(0);

    f32x16 acc;
    for (int chunk = 0; chunk < NCHUNK; ++chunk) {
#pragma unroll
        for (int r = 0; r < 16; ++r) acc[r] = 0.0f;

#pragma unroll
        for (int k4 = 0; k4 < 4; ++k4) {
            const int s = chunk * 4 + k4;
            const int snext = s + 1;
            if (snext < NSTG) {
                ISSUE_STAGE(snext);
                asm volatile("s_waitcnt vmcnt(8)" ::: "memory");  // stage-s loads landed
            } else {
                asm volatile("s_waitcnt vmcnt(0)" ::: "memory");
            }
            __builtin_amdgcn_sched_barrier(0);
            __builtin_amdgcn_s_barrier();        // buf[s&1] ready for all waves
            __builtin_amdgcn_sched_barrier(0);

            const int bcur = k4 & 1;
#pragma unroll
            for (int t = 0; t < 4; ++t) {
                const int kt = k4 * 4 + t;
                const char* ph = bbuf + (((bcur << 4) + 0 + (t << 1) + lh) << 12)
                                      + ((wid * 32 + lm) << 4);
                const char* pl = bbuf + (((bcur << 4) + 8 + (t << 1) + lh) << 12)
                                      + ((wid * 32 + lm) << 4);
                const short8v bh = *(const short8v*)ph;
                const short8v bl = *(const short8v*)pl;
                acc = __builtin_amdgcn_mfma_f32_32x32x16_bf16(ahi[kt], bh, acc, 0, 0, 0);
                acc = __builtin_amdgcn_mfma_f32_32x32x16_bf16(ahi[kt], bl, acc, 0, 0, 0);
                acc = __builtin_amdgcn_mfma_f32_32x32x16_bf16(alo[kt], bh, acc, 0, 0, 0);
            }
            __builtin_amdgcn_sched_barrier(0);
            __builtin_amdgcn_s_barrier();        // all reads of buf[s&1] done
            __builtin_amdgcn_sched_barrier(0);
        }

        // ---- selection for completed 256-col chunk (v2 structure, proven)
        const int colbase = chunk * 256 + wid * 32 + lm;   // this lane's j (all 16 regs)
        unsigned pend = 0xFFFFu;
        for (;;) {
#pragma unroll
            for (int r = 0; r < 16; ++r) {
                if (pend & (1u << r)) {
                    const int row = (r & 3) + ((r >> 2) << 3) + (lh << 2);
                    const float v = acc[r];
                    if (v > topmin[row]) {
                        const int p = atomicAdd(&qcnt[row], 1);
                        if (p < QCAP) {
                            qv[row][p] = v;
                            qj[row][p] = colbase;
                            pend &= ~(1u << r);
                        }
                    } else {
                        pend &= ~(1u << r);
                    }
                }
            }
            __syncthreads();              // queues ready
            if (tid < 32) {
                const int row = tid;
                int n = qcnt[row];
                if (n > QCAP) { ovf_flag = 1; n = QCAP; }
                for (int q = 0; q < n; ++q) {
                    const float v = qv[row][q];
                    if (v > topv[row][KNB - 1]) {
                        const int jjx = qj[row][q];
                        int p = KNB - 1;
                        while (p > 0 && topv[row][p - 1] < v) {
                            topv[row][p] = topv[row][p - 1];
                            topi[row][p] = topi[row][p - 1];
                            --p;
                        }
                        topv[row][p] = v;
                        topi[row][p] = jjx;
                    }
                }
                topmin[row] = topv[row][KNB - 1];
                qcnt[row] = 0;
            }
            __syncthreads();              // flag final
            const int f = ovf_flag;       // uniform read
            __syncthreads();              // everyone has read
            if (tid == 0) ovf_flag = 0;
            if (!f) break;
        }
    }
#undef ISSUE_STAGE

    // ---- softmax over kept 32 values, write weights + indices
    if (tid < 32) {
        const int row = tid;
        const float m = topv[row][0];
        float w[KNB];
        float s = 0.0f;
#pragma unroll
        for (int q = 0; q < KNB; ++q) { w[q] = __expf(topv[row][q] - m); s += w[q]; }
        const float inv = 1.0f / s;
#pragma unroll
        for (int q = 0; q < KNB; ++q) {
            topw[(size_t)(i0 + row) * KNB + q] = w[q] * inv;
            topig[(size_t)(i0 + row) * KNB + q] = topi[row][q];
        }
    }
}

// ---------------------------------------------------------------------------
// out[i] = X[i] + gc_b + sum_m w[i][m] * H[idx[i][m]]
// ---------------------------------------------------------------------------
__global__ __launch_bounds__(256) void gather_kernel(const float* __restrict__ X,
                                                     const float* __restrict__ H,
                                                     const float* __restrict__ topw,
                                                     const int* __restrict__ topig,
                                                     const float* __restrict__ gc_b,
                                                     float* __restrict__ out) {
    __shared__ float w[KNB];
    __shared__ int   id[KNB];
    const int row = blockIdx.x;
    const int t = threadIdx.x;
    if (t < KNB) {
        w[t] = topw[(size_t)row * KNB + t];
        id[t] = topig[(size_t)row * KNB + t];
    }
    __syncthreads();
    const int col = t * 4;
    float4 acc = *reinterpret_cast<const float4*>(X + (size_t)row * D1 + col);
    const float4 b = *reinterpret_cast<const float4*>(gc_b + col);
    acc.x += b.x; acc.y += b.y; acc.z += b.z; acc.w += b.w;
#pragma unroll 8
    for (int m = 0; m < KNB; ++m) {
        const float wm = w[m];
        const float4 h = *reinterpret_cast<const float4*>(H + (size_t)id[m] * D1 + col);
        acc.x += wm * h.x; acc.y += wm * h.y; acc.z += wm * h.z; acc.w += wm * h.w;
    }
    *reinterpret_cast<float4*>(out + (size_t)row * D1 + col) = acc;
}

// ---------------------------------------------------------------------------
extern "C" void kernel_launch(void* const* d_in, const int* in_sizes, int n_in,
                              void* d_out, int out_size, void* d_ws, size_t ws_size,
                              hipStream_t stream) {
    const float* X  = (const float*)d_in[0];
    const float* lg = (const float*)d_in[1];
    const float* lb = (const float*)d_in[2];
    const float* fw = (const float*)d_in[3];
    const float* fb = (const float*)d_in[4];
    const float* gw = (const float*)d_in[5];
    const float* gb = (const float*)d_in[6];
    float* out = (float*)d_out;

    // workspace layout (bytes total = 85,983,232; identical to v2's footprint)
    const size_t szX1 = (size_t)N_ROWS * D1;   // f32
    const size_t szXf = (size_t)N_ROWS * DF;   // f32
    const size_t need = szX1 * 4 + szXf * 4 + szXf * 2 * 2 + szX1 * 4
                      + (size_t)N_ROWS * KNB * 8;
    if (ws_size < need) return;

    float* X1 = (float*)d_ws;
    float* Xf = X1 + szX1;
    __hip_bfloat16* xhi = (__hip_bfloat16*)(Xf + szXf);
    __hip_bfloat16* xlo = xhi + szXf;
    float* H  = (float*)(xlo + szXf);
    float* tw = H + szX1;
    int*   ti = (int*)(tw + (size_t)N_ROWS * KNB);

    ln_kernel<<<N_ROWS, 256, 0, stream>>>(X, lg, lb, X1);
    gemm128<true, true><<<dim3(DF / 128, N_ROWS / 128), 256, 0, stream>>>(X1, fw, fb, Xf, N_ROWS, DF, D1);
    rownorm_kernel<<<N_ROWS, 256, 0, stream>>>(Xf, xhi, xlo);
    sim_topk_kernel<<<N_ROWS / 32, 512, 0, stream>>>(xhi, xlo, tw, ti);
    gemm128<false, false><<<dim3(D1 / 128, N_ROWS / 128), 256, 0, stream>>>(X1, gw, nullptr, H, N_ROWS, D1, D1);
    gather_kernel<<<N_ROWS, 256, 0, stream>>>(X, H, tw, ti, gb, out);
}

// Round 9
// 1331.625 us; speedup vs baseline: 1.7028x; 1.1252x over previous
//
#include <hip/hip_runtime.h>
#include <hip/hip_bf16.h>

// Problem constants
#define N_ROWS 8192
#define D1     1024
#define DF     256
#define KNB    32
#define LN_EPS 1e-5f

typedef unsigned short ushort_t;
typedef __attribute__((ext_vector_type(8)))  short short8v;   // 8 bf16 (4 VGPRs)
typedef __attribute__((ext_vector_type(16))) float f32x16;    // MFMA 32x32 accumulator

// ---------------------------------------------------------------------------
// LayerNorm: one block per row, 256 threads, 4 floats/thread (float4)
// ---------------------------------------------------------------------------
__global__ __launch_bounds__(256) void ln_kernel(const float* __restrict__ X,
                                                 const float* __restrict__ gamma,
                                                 const float* __restrict__ beta,
                                                 float* __restrict__ X1) {
    __shared__ float sa[4], sb[4];
    const int row = blockIdx.x;
    const int t = threadIdx.x;
    const float4 x = reinterpret_cast<const float4*>(X + (size_t)row * D1)[t];
    float s  = x.x + x.y + x.z + x.w;
    float ss = x.x * x.x + x.y * x.y + x.z * x.z + x.w * x.w;
#pragma unroll
    for (int o = 32; o > 0; o >>= 1) {
        s  += __shfl_down(s, o, 64);
        ss += __shfl_down(ss, o, 64);
    }
    const int w = t >> 6, l = t & 63;
    if (l == 0) { sa[w] = s; sb[w] = ss; }
    __syncthreads();
    s  = sa[0] + sa[1] + sa[2] + sa[3];
    ss = sb[0] + sb[1] + sb[2] + sb[3];
    const float mu  = s * (1.0f / D1);
    const float var = ss * (1.0f / D1) - mu * mu;
    const float rs  = rsqrtf(var + LN_EPS);
    const float4 g  = reinterpret_cast<const float4*>(gamma)[t];
    const float4 be = reinterpret_cast<const float4*>(beta)[t];
    float4 o;
    o.x = (x.x - mu) * rs * g.x + be.x;
    o.y = (x.y - mu) * rs * g.y + be.y;
    o.z = (x.z - mu) * rs * g.z + be.z;
    o.w = (x.w - mu) * rs * g.w + be.w;
    reinterpret_cast<float4*>(X1 + (size_t)row * D1)[t] = o;
}

// ---------------------------------------------------------------------------
// fp32 tiled GEMM (unchanged — handles fc and gc matmuls)
// ---------------------------------------------------------------------------
template <bool TRANSB, bool BIAS>
__global__ __launch_bounds__(256) void gemm128(const float* __restrict__ A,
                                               const float* __restrict__ B,
                                               const float* __restrict__ bias,
                                               float* __restrict__ C,
                                               int M, int N, int K) {
    __shared__ float As[16][128];
    __shared__ float Bs[16][128];
    const int tid = threadIdx.x;
    const int bn = blockIdx.x * 128;
    const int bm = blockIdx.y * 128;
    const int tx = tid & 15, ty = tid >> 4;

    float acc[8][8];
#pragma unroll
    for (int i = 0; i < 8; ++i)
#pragma unroll
        for (int j = 0; j < 8; ++j) acc[i][j] = 0.0f;

    for (int k0 = 0; k0 < K; k0 += 16) {
#pragma unroll
        for (int c = 0; c < 2; ++c) {
            int idx = c * 256 + tid;
            int m = idx & 127, kg = idx >> 7;
            float4 v = *reinterpret_cast<const float4*>(A + (size_t)(bm + m) * K + k0 + kg * 4);
            As[kg * 4 + 0][m] = v.x;
            As[kg * 4 + 1][m] = v.y;
            As[kg * 4 + 2][m] = v.z;
            As[kg * 4 + 3][m] = v.w;
        }
        if (TRANSB) {
#pragma unroll
            for (int c = 0; c < 2; ++c) {
                int idx = c * 256 + tid;
                int n = idx & 127, kg = idx >> 7;
                float4 v = *reinterpret_cast<const float4*>(B + (size_t)(bn + n) * K + k0 + kg * 4);
                Bs[kg * 4 + 0][n] = v.x;
                Bs[kg * 4 + 1][n] = v.y;
                Bs[kg * 4 + 2][n] = v.z;
                Bs[kg * 4 + 3][n] = v.w;
            }
        } else {
#pragma unroll
            for (int c = 0; c < 2; ++c) {
                int idx = c * 256 + tid;
                int n4 = idx & 31, kk = idx >> 5;
                float4 v = *reinterpret_cast<const float4*>(B + (size_t)(k0 + kk) * N + bn + n4 * 4);
                *reinterpret_cast<float4*>(&Bs[kk][n4 * 4]) = v;
            }
        }
        __syncthreads();
#pragma unroll
        for (int kk = 0; kk < 16; ++kk) {
            float a[8], b[8];
            *reinterpret_cast<float4*>(&a[0]) = *reinterpret_cast<const float4*>(&As[kk][ty * 8]);
            *reinterpret_cast<float4*>(&a[4]) = *reinterpret_cast<const float4*>(&As[kk][ty * 8 + 4]);
            *reinterpret_cast<float4*>(&b[0]) = *reinterpret_cast<const float4*>(&Bs[kk][tx * 8]);
            *reinterpret_cast<float4*>(&b[4]) = *reinterpret_cast<const float4*>(&Bs[kk][tx * 8 + 4]);
#pragma unroll
            for (int i = 0; i < 8; ++i)
#pragma unroll
                for (int j = 0; j < 8; ++j) acc[i][j] += a[i] * b[j];
        }
        __syncthreads();
    }

#pragma unroll
    for (int i = 0; i < 8; ++i) {
        const int m = bm + ty * 8 + i;
        float* cp = C + (size_t)m * N + bn + tx * 8;
        float4 v0, v1;
        v0.x = acc[i][0]; v0.y = acc[i][1]; v0.z = acc[i][2]; v0.w = acc[i][3];
        v1.x = acc[i][4]; v1.y = acc[i][5]; v1.z = acc[i][6]; v1.w = acc[i][7];
        if (BIAS) {
            const float4 b0 = *reinterpret_cast<const float4*>(bias + bn + tx * 8);
            const float4 b1 = *reinterpret_cast<const float4*>(bias + bn + tx * 8 + 4);
            v0.x += b0.x; v0.y += b0.y; v0.z += b0.z; v0.w += b0.w;
            v1.x += b1.x; v1.y += b1.y; v1.z += b1.z; v1.w += b1.w;
        }
        *reinterpret_cast<float4*>(cp) = v0;
        *reinterpret_cast<float4*>(cp + 4) = v1;
    }
}

// ---------------------------------------------------------------------------
// Row L2-normalize + split-bf16 emit in WINDOW-MAJOR layout:
//   Q[w][j] = 16B chunk holding bf16 Xn[j][8w .. 8w+8),  w = 0..31.
// This makes the sim kernel's stage loads lane-consecutive (coalesced).
// One block per row, 256 threads. LDS transpose then 16B chunk stores.
// ---------------------------------------------------------------------------
__global__ __launch_bounds__(256) void rownorm_kernel(const float* __restrict__ Xf,
                                                      ushort_t* __restrict__ Qhi,
                                                      ushort_t* __restrict__ Qlo) {
    __shared__ float sa[4];
    __shared__ ushort_t hs[256], ls[256];
    const int row = blockIdx.x;
    const int t = threadIdx.x;
    const float v = Xf[(size_t)row * DF + t];
    float ss = v * v;
#pragma unroll
    for (int o = 32; o > 0; o >>= 1) ss += __shfl_down(ss, o, 64);
    const int w = t >> 6, l = t & 63;
    if (l == 0) sa[w] = ss;
    __syncthreads();
    ss = sa[0] + sa[1] + sa[2] + sa[3];
    const float inv = 1.0f / sqrtf(ss);
    const float xn = v * inv;
    const __hip_bfloat16 h = __float2bfloat16(xn);
    const float hf = __bfloat162float(h);
    const __hip_bfloat16 lo = __float2bfloat16(xn - hf);
    hs[t] = *(const ushort_t*)&h;
    ls[t] = *(const ushort_t*)&lo;
    __syncthreads();
    if (t < 32) {                       // window w = t  -> Qhi[w][row]
        ushort_t tmp[8];
#pragma unroll
        for (int e = 0; e < 8; ++e) tmp[e] = hs[t * 8 + e];
        *reinterpret_cast<int4*>(Qhi + ((size_t)t * N_ROWS + row) * 8) =
            *reinterpret_cast<const int4*>(tmp);
    } else if (t < 64) {                // window w = t-32 -> Qlo[w][row]
        const int ww = t - 32;
        ushort_t tmp[8];
#pragma unroll
        for (int e = 0; e < 8; ++e) tmp[e] = ls[ww * 8 + e];
        *reinterpret_cast<int4*>(Qlo + ((size_t)ww * N_ROWS + row) * 8) =
            *reinterpret_cast<const int4*>(tmp);
    }
}

// ---------------------------------------------------------------------------
// Fused sim GEMM + top-32 + softmax, v4: split-bf16 MFMA with window-major
// coalesced staging. S = hi·hi + hi·lo + lo·hi (err ~2^-16, selection-safe).
// Block = 32 rows, 512 threads = 8 waves; wave owns a 32-col group per chunk.
// A hi/lo fragments for full K=256 in registers. B staged per 256-col x 64-k
// stage via global_load_lds (16B): src = Q[w][jbase+lane] -> lane-consecutive
// (coalesced); LDS dest linear, frag-native [slot][j] -> conflict-free
// ds_read_b128. Double-buffered, counted vmcnt(8), raw s_barrier fences.
// Selection: proven queue + serial-insert + retry (v2/v3 verbatim).
//
// MFMA layouts (m74/m101 verified, 32x32x16_bf16):
//   A: row = lane&31, k = (lane>>5)*8 + i
//   B: col = lane&31, k = (lane>>5)*8 + i
//   C: col = lane&31, row = (reg&3) + 8*(reg>>2) + 4*(lane>>5)
// ---------------------------------------------------------------------------
#define QCAP   64
#define NCHUNK 32     // 8192 / 256 cols
#define NSTG   128    // NCHUNK * 4 k-stages (64 k = 8 windows each)

__global__ __launch_bounds__(512, 2) void sim_topk_kernel(
        const ushort_t* __restrict__ Qhi,
        const ushort_t* __restrict__ Qlo,
        float* __restrict__ topw,
        int* __restrict__ topig) {
    // B buffers: [buf 2][hl 2][slot 8][j 256][16B] = 128 KB
    __shared__ char  bbuf[131072];
    __shared__ float topv[32][KNB + 1];
    __shared__ int   topi[32][KNB + 1];
    __shared__ float qv[32][QCAP + 1];
    __shared__ int   qj[32][QCAP + 1];
    __shared__ float topmin[32];
    __shared__ int   qcnt[32];
    __shared__ int   ovf_flag;

    const int tid  = threadIdx.x;
    const int lane = tid & 63;
    const int wid  = tid >> 6;       // wave 0..7 -> cols wid*32..wid*32+31 of chunk
    const int lh   = lane >> 5;      // k-half selector / C-row offset
    const int lm   = lane & 31;
    const int i0   = blockIdx.x * 32;

    // ---- A fragments in registers: 16 k-tiles x {hi,lo}
    // frag (kt,lh): window w = kt*2+lh, row j = i0+lm -> Q[(w*8192 + j)*8]
    short8v ahi[16], alo[16];
#pragma unroll
    for (int kt = 0; kt < 16; ++kt) {
        const size_t off = ((size_t)(kt * 2 + lh) * N_ROWS + i0 + lm) * 8;
        ahi[kt] = *(const short8v*)(Qhi + off);
        alo[kt] = *(const short8v*)(Qlo + off);
    }

    // ---- selection init
    if (tid < 32) {
        qcnt[tid] = 0;
        topmin[tid] = -__builtin_inff();
#pragma unroll
        for (int m = 0; m < KNB; ++m) { topv[tid][m] = -__builtin_inff(); topi[tid][m] = -1; }
    }
    if (tid == 0) ovf_flag = 0;
    __syncthreads();   // full fence: init done

    // stage S: chunk cn = S>>2, window base wb = (S&3)*8. Each wave issues 8
    // global_load_lds(16B): gi = wid*8+q -> slot-class sc = gi>>2 (hl*8+slot),
    // g = gi&3 (j-group of 64). src lane-consecutive in Q[w][.] (coalesced);
    // LDS dest linear (wave-uniform base + lane*16).
#define ISSUE_STAGE(S) do {                                                          \
        const int cn_ = (S) >> 2;                                                    \
        const int wb_ = ((S) & 3) * 8;                                               \
        const int b_  = (S) & 1;                                                     \
        _Pragma("unroll")                                                            \
        for (int q = 0; q < 8; ++q) {                                                \
            const int gi   = (wid << 3) + q;                                         \
            const int sc   = gi >> 2;                                                \
            const int g    = gi & 3;                                                 \
            const int hl   = sc >> 3;                                                \
            const int slot = sc & 7;                                                 \
            const ushort_t* src = (hl ? Qlo : Qhi)                                   \
                + ((size_t)(wb_ + slot) * N_ROWS + cn_ * 256 + g * 64 + lane) * 8;   \
            char* dst = bbuf + (((b_ << 4) + (hl << 3) + slot) << 12) + (g << 10);   \
            __builtin_amdgcn_global_load_lds(                                        \
                (const __attribute__((address_space(1))) unsigned int*)src,          \
                (__attribute__((address_space(3))) unsigned int*)dst, 16, 0, 0);     \
        }                                                                            \
    } while (0)

    ISSUE_STAGE(0);

    f32x16 acc;
    for (int chunk = 0; chunk < NCHUNK; ++chunk) {
#pragma unroll
        for (int r = 0; r < 16; ++r) acc[r] = 0.0f;

#pragma unroll
        for (int k4 = 0; k4 < 4; ++k4) {
            const int s = chunk * 4 + k4;
            const int snext = s + 1;
            if (snext < NSTG) {
                ISSUE_STAGE(snext);
                asm volatile("s_waitcnt vmcnt(8)" ::: "memory");  // stage-s loads landed
            } else {
                asm volatile("s_waitcnt vmcnt(0)" ::: "memory");
            }
            __builtin_amdgcn_sched_barrier(0);
            __builtin_amdgcn_s_barrier();        // buf[s&1] ready for all waves
            __builtin_amdgcn_sched_barrier(0);

            const int bcur = k4 & 1;
#pragma unroll
            for (int t = 0; t < 4; ++t) {
                const int kt = k4 * 4 + t;
                const char* ph = bbuf + (((bcur << 4) + 0 + (t << 1) + lh) << 12)
                                      + ((wid * 32 + lm) << 4);
                const char* pl = bbuf + (((bcur << 4) + 8 + (t << 1) + lh) << 12)
                                      + ((wid * 32 + lm) << 4);
                const short8v bh = *(const short8v*)ph;
                const short8v bl = *(const short8v*)pl;
                acc = __builtin_amdgcn_mfma_f32_32x32x16_bf16(ahi[kt], bh, acc, 0, 0, 0);
                acc = __builtin_amdgcn_mfma_f32_32x32x16_bf16(ahi[kt], bl, acc, 0, 0, 0);
                acc = __builtin_amdgcn_mfma_f32_32x32x16_bf16(alo[kt], bh, acc, 0, 0, 0);
            }
            __builtin_amdgcn_sched_barrier(0);
            __builtin_amdgcn_s_barrier();        // all reads of buf[s&1] done
            __builtin_amdgcn_sched_barrier(0);
        }

        // ---- selection for completed 256-col chunk (proven v2 structure)
        const int colbase = chunk * 256 + wid * 32 + lm;   // this lane's j
        unsigned pend = 0xFFFFu;
        for (;;) {
#pragma unroll
            for (int r = 0; r < 16; ++r) {
                if (pend & (1u << r)) {
                    const int row = (r & 3) + ((r >> 2) << 3) + (lh << 2);
                    const float v = acc[r];
                    if (v > topmin[row]) {
                        const int p = atomicAdd(&qcnt[row], 1);
                        if (p < QCAP) {
                            qv[row][p] = v;
                            qj[row][p] = colbase;
                            pend &= ~(1u << r);
                        }
                    } else {
                        pend &= ~(1u << r);
                    }
                }
            }
            __syncthreads();              // queues ready
            if (tid < 32) {
                const int row = tid;
                int n = qcnt[row];
                if (n > QCAP) { ovf_flag = 1; n = QCAP; }
                for (int q = 0; q < n; ++q) {
                    const float v = qv[row][q];
                    if (v > topv[row][KNB - 1]) {
                        const int jjx = qj[row][q];
                        int p = KNB - 1;
                        while (p > 0 && topv[row][p - 1] < v) {
                            topv[row][p] = topv[row][p - 1];
                            topi[row][p] = topi[row][p - 1];
                            --p;
                        }
                        topv[row][p] = v;
                        topi[row][p] = jjx;
                    }
                }
                topmin[row] = topv[row][KNB - 1];
                qcnt[row] = 0;
            }
            __syncthreads();              // flag final
            const int f = ovf_flag;       // uniform read
            __syncthreads();              // everyone has read
            if (tid == 0) ovf_flag = 0;
            if (!f) break;
        }
    }
#undef ISSUE_STAGE

    // ---- softmax over kept 32 values, write weights + indices
    if (tid < 32) {
        const int row = tid;
        const float m = topv[row][0];
        float w[KNB];
        float s = 0.0f;
#pragma unroll
        for (int q = 0; q < KNB; ++q) { w[q] = __expf(topv[row][q] - m); s += w[q]; }
        const float inv = 1.0f / s;
#pragma unroll
        for (int q = 0; q < KNB; ++q) {
            topw[(size_t)(i0 + row) * KNB + q] = w[q] * inv;
            topig[(size_t)(i0 + row) * KNB + q] = topi[row][q];
        }
    }
}

// ---------------------------------------------------------------------------
// out[i] = X[i] + gc_b + sum_m w[i][m] * H[idx[i][m]]
// ---------------------------------------------------------------------------
__global__ __launch_bounds__(256) void gather_kernel(const float* __restrict__ X,
                                                     const float* __restrict__ H,
                                                     const float* __restrict__ topw,
                                                     const int* __restrict__ topig,
                                                     const float* __restrict__ gc_b,
                                                     float* __restrict__ out) {
    __shared__ float w[KNB];
    __shared__ int   id[KNB];
    const int row = blockIdx.x;
    const int t = threadIdx.x;
    if (t < KNB) {
        w[t] = topw[(size_t)row * KNB + t];
        id[t] = topig[(size_t)row * KNB + t];
    }
    __syncthreads();
    const int col = t * 4;
    float4 acc = *reinterpret_cast<const float4*>(X + (size_t)row * D1 + col);
    const float4 b = *reinterpret_cast<const float4*>(gc_b + col);
    acc.x += b.x; acc.y += b.y; acc.z += b.z; acc.w += b.w;
#pragma unroll 8
    for (int m = 0; m < KNB; ++m) {
        const float wm = w[m];
        const float4 h = *reinterpret_cast<const float4*>(H + (size_t)id[m] * D1 + col);
        acc.x += wm * h.x; acc.y += wm * h.y; acc.z += wm * h.z; acc.w += wm * h.w;
    }
    *reinterpret_cast<float4*>(out + (size_t)row * D1 + col) = acc;
}

// ---------------------------------------------------------------------------
extern "C" void kernel_launch(void* const* d_in, const int* in_sizes, int n_in,
                              void* d_out, int out_size, void* d_ws, size_t ws_size,
                              hipStream_t stream) {
    const float* X  = (const float*)d_in[0];
    const float* lg = (const float*)d_in[1];
    const float* lb = (const float*)d_in[2];
    const float* fw = (const float*)d_in[3];
    const float* fb = (const float*)d_in[4];
    const float* gw = (const float*)d_in[5];
    const float* gb = (const float*)d_in[6];
    float* out = (float*)d_out;

    // workspace layout (same footprint as v3; Qhi/Qlo replace xhi/xlo)
    const size_t szX1 = (size_t)N_ROWS * D1;   // f32
    const size_t szXf = (size_t)N_ROWS * DF;   // f32
    const size_t need = szX1 * 4 + szXf * 4 + szXf * 2 * 2 + szX1 * 4
                      + (size_t)N_ROWS * KNB * 8;
    if (ws_size < need) return;

    float* X1 = (float*)d_ws;
    float* Xf = X1 + szX1;
    ushort_t* Qhi = (ushort_t*)(Xf + szXf);    // [32][8192] 16B chunks = 4MB
    ushort_t* Qlo = Qhi + szXf;                // 4MB
    float* H  = (float*)(Qlo + szXf);
    float* tw = H + szX1;
    int*   ti = (int*)(tw + (size_t)N_ROWS * KNB);

    ln_kernel<<<N_ROWS, 256, 0, stream>>>(X, lg, lb, X1);
    gemm128<true, true><<<dim3(DF / 128, N_ROWS / 128), 256, 0, stream>>>(X1, fw, fb, Xf, N_ROWS, DF, D1);
    rownorm_kernel<<<N_ROWS, 256, 0, stream>>>(Xf, Qhi, Qlo);
    sim_topk_kernel<<<N_ROWS / 32, 512, 0, stream>>>(Qhi, Qlo, tw, ti);
    gemm128<false, false><<<dim3(D1 / 128, N_ROWS / 128), 256, 0, stream>>>(X1, gw, nullptr, H, N_ROWS, D1, D1);
    gather_kernel<<<N_ROWS, 256, 0, stream>>>(X, H, tw, ti, gb, out);
}